// Round 5
// baseline (338.887 us; speedup 1.0000x reference)
//
#include <hip/hip_runtime.h>

// GateRecurrent2dnoind: left-to-right SPN scan over W, 3-pt stencil along H.
// [N=8, C=64, H=256, W=256] fp32.
//
// One single-wave block per (n,c) plane. Lane l owns rows 4l..4l+3 ->
// vertical exchange = 2 shuffles/step, zero barriers. Staging via
// global_load_lds with line-covering lane groups (8 lanes = 4 rows x 32B)
// and a per-lane XOR pre-swizzle of the global source so scan-side
// ds_read_b128 (slot 8l + ((2r+CG)^(l&7))) is phase-balanced.
// R5 change: 2 half-buffers (64 KB LDS) instead of 4 (128 KB) -> 2 blocks/CU,
// all 512 waves resident in ONE round (R4 ran 2 rounds of 1 wave/CU).
// Counted vmcnt ledger: WAITV(32) t<2, WAITV(48) steady, WAITV(16) at t=31.

constexpr int H  = 256;
constexpr int W  = 256;
constexpr int HC = 8;           // cols per half-tile
constexpr int NH = W / HC;      // 32 half-tiles

#define F4C(v, j) ((&(v).x)[j])
#define WAITV(N) asm volatile("s_waitcnt vmcnt(" #N ")" ::: "memory")

typedef const __attribute__((address_space(1))) void* gas_ptr;
typedef __attribute__((address_space(3))) void* las_ptr;

__device__ __forceinline__ void gl16(const float* g, float4* l) {
    __builtin_amdgcn_global_load_lds((gas_ptr)(const void*)g, (las_ptr)(void*)l,
                                     16, 0, 0);
}

struct Ptrs { const float *i0, *i1, *i2, *i3; };

// issue the 32 global->LDS loads of half-tile h into buf (4 arrays x 512 slots)
__device__ __forceinline__
void issue_half(const Ptrs& P, float4 (*buf)[512], int h)
{
    const int base = h * HC;
#pragma unroll
    for (int i = 0; i < 8; ++i) {
        const int go = base + i * (32 * W);    // rows 32i..32i+31
        gl16(P.i0 + go, &buf[0][i * 64]);
        gl16(P.i1 + go, &buf[1][i * 64]);
        gl16(P.i2 + go, &buf[2][i * 64]);
        gl16(P.i3 + go, &buf[3][i * 64]);
    }
}

// one half-tile: 32 ds_read_b128 -> lgkmcnt(0) -> issue next half into the
// SAME buffer (now free) -> 8 sequential scan steps. OCB = o[] col-group base.
template<int OCB>
__device__ __forceinline__
void iter_body(const float4 (*A)[512], const Ptrs& P, float4 (*nextbuf)[512],
               int hnext, bool do_issue, int l, int lx,
               float& h0, float& h1, float& h2, float& h3, float4 o[4][4])
{
    float4 q[2][4][4];                    // [CG][row r][array a]
    const int s8 = 8 * l;
#pragma unroll
    for (int CG = 0; CG < 2; ++CG)
#pragma unroll
        for (int r = 0; r < 4; ++r) {
            const int sl = s8 + ((2 * r + CG) ^ lx);
#pragma unroll
            for (int a = 0; a < 4; ++a)
                q[CG][r][a] = A[a][sl];
        }

    asm volatile("s_waitcnt lgkmcnt(0)" ::: "memory");  // buffer free to overwrite
    __builtin_amdgcn_sched_barrier(0);
    if (do_issue) issue_half(P, nextbuf, hnext);

#pragma unroll
    for (int CG = 0; CG < 2; ++CG) {
#pragma unroll
        for (int j = 0; j < 4; ++j) {
            float up = __shfl_up(h3, 1);            // lane-1's row 4l-1
            float dn = __shfl_down(h0, 1);          // lane+1's row 4l+4
            if (l == 0)  up = 0.f;
            if (l == 63) dn = 0.f;

            const float x0 = F4C(q[CG][0][0], j), a10 = F4C(q[CG][0][1], j),
                        a20 = F4C(q[CG][0][2], j), a30 = F4C(q[CG][0][3], j);
            const float x1 = F4C(q[CG][1][0], j), a11 = F4C(q[CG][1][1], j),
                        a21 = F4C(q[CG][1][2], j), a31 = F4C(q[CG][1][3], j);
            const float x2 = F4C(q[CG][2][0], j), a12 = F4C(q[CG][2][1], j),
                        a22 = F4C(q[CG][2][2], j), a32 = F4C(q[CG][2][3], j);
            const float x3 = F4C(q[CG][3][0], j), a13 = F4C(q[CG][3][1], j),
                        a23 = F4C(q[CG][3][2], j), a33 = F4C(q[CG][3][3], j);

            const float n0 = fmaf(a30, h1, fmaf(a20, h0,
                             fmaf(a10, up, x0 * (1.f - a10 - a20 - a30))));
            const float n1 = fmaf(a31, h2, fmaf(a21, h1,
                             fmaf(a11, h0, x1 * (1.f - a11 - a21 - a31))));
            const float n2 = fmaf(a32, h3, fmaf(a22, h2,
                             fmaf(a12, h1, x2 * (1.f - a12 - a22 - a32))));
            const float n3 = fmaf(a33, dn, fmaf(a23, h3,
                             fmaf(a13, h2, x3 * (1.f - a13 - a23 - a33))));

            h0 = n0; h1 = n1; h2 = n2; h3 = n3;
            F4C(o[0][OCB + CG], j) = n0;
            F4C(o[1][OCB + CG], j) = n1;
            F4C(o[2][OCB + CG], j) = n2;
            F4C(o[3][OCB + CG], j) = n3;
        }
    }
}

__global__ __launch_bounds__(64)
void spn_wave(const float* __restrict__ X,  const float* __restrict__ G1,
              const float* __restrict__ G2, const float* __restrict__ G3,
              float* __restrict__ O)
{
    __shared__ float4 lds4[2][4][512];   // [buf][array][16B slot] = 64 KiB

    const int l  = threadIdx.x;          // 0..63
    const int lx = l & 7;
    const size_t pb = (size_t)blockIdx.x * (size_t)(H * W);

    // inverse-swizzled per-lane global offset (granule jp = R_local*2 + cc)
    const int jp      = l ^ ((l >> 3) & 7);
    const int laneoff = (jp >> 1) * W + (jp & 1) * 4;

    const Ptrs P{ X + pb + laneoff, G1 + pb + laneoff,
                  G2 + pb + laneoff, G3 + pb + laneoff };
    float* out = O + pb + (size_t)(4 * l) * W;

    issue_half(P, lds4[0], 0);
    issue_half(P, lds4[1], 1);

    float h0 = 0.f, h1 = 0.f, h2 = 0.f, h3 = 0.f;
    float4 o[4][4];                      // [row r][col-group]

#pragma unroll 1
    for (int p = 0; p < 16; ++p) {
        // ---- t = 2p (buf 0, o cols 0..1) ----
        if (p == 0) WAITV(32); else WAITV(48);
        iter_body<0>(lds4[0], P, lds4[0], 2 * p + 2, p < 15, l, lx,
                     h0, h1, h2, h3, o);

        // ---- t = 2p+1 (buf 1, o cols 2..3) ----
        if (p == 0) WAITV(32); else if (p == 15) WAITV(16); else WAITV(48);
        iter_body<2>(lds4[1], P, lds4[1], 2 * p + 3, p < 15, l, lx,
                     h0, h1, h2, h3, o);

        // ---- store 16 cols x 4 rows (full 64B per row) ----
        const int wp = p * 16;
#pragma unroll
        for (int r = 0; r < 4; ++r) {
            float* po = out + r * W + wp;
            *reinterpret_cast<float4*>(po +  0) = o[r][0];
            *reinterpret_cast<float4*>(po +  4) = o[r][1];
            *reinterpret_cast<float4*>(po +  8) = o[r][2];
            *reinterpret_cast<float4*>(po + 12) = o[r][3];
        }
    }
}

extern "C" void kernel_launch(void* const* d_in, const int* in_sizes, int n_in,
                              void* d_out, int out_size, void* d_ws, size_t ws_size,
                              hipStream_t stream) {
    const float* X  = (const float*)d_in[0];
    const float* G1 = (const float*)d_in[1];
    const float* G2 = (const float*)d_in[2];
    const float* G3 = (const float*)d_in[3];
    float* O = (float*)d_out;

    const int planes = 8 * 64;   // 512 single-wave blocks, 2 per CU, one round
    spn_wave<<<dim3(planes), dim3(64), 0, stream>>>(X, G1, G2, G3, O);
}